// Round 1
// baseline (236.464 us; speedup 1.0000x reference)
//
#include <hip/hip_runtime.h>
#include <math.h>

// DiceLoss: B=8, C=19, H=W=512. logits fp32 [B,C,H,W], targets int [B,H,W].
// Round 8: in-flight congruence limiting. Round 7's nt-load was a null
// (229.4 vs 230.0) -> L1 *policy* is irrelevant (every byte is consumed
// into VGPRs exactly once). Surviving theory: the 19 back-to-back Phase-A
// loads differ only in address bits >=20 (channel stride 2^20), so all 19
// in-flight requests per wave alias the same L1 sets / MSHR slots / DRAM
// bank bits -> ~19-way structural serialization (~1 line/21cy observed).
// Fix: software-pipeline the channel loads in groups of 3, two groups in
// flight, consuming (exp + denom partial sum) each group on arrival.
// sched_barrier(0) fences pin the issue order. Per-wave congruent in-flight
// drops 20 -> <=7. MLP stays ample: 8 waves/CU x 6KiB ~ 128 GB/s/CU >> the
// 24.6 GB/s/CU needed at peak. FP accumulation order is unchanged
// (s0..s3 still sum channels 0..18 in order) -> bit-identical output.

#define CC 19
#define HWBITS 18
#define HHWW (1 << HWBITS)            // 262144
#define NPIX (8 * HHWW)               // 2,097,152
#define QPP (HHWW / 4)                // 65536 float4-quads per channel plane
#define NQUAD (NPIX / 4)              // 524288
#define NBLK 1024
#define NTHR 256
#define NTH_TOT (NBLK * NTHR)         // 262144
#define NITER (NQUAD / NTH_TOT)       // 2, exact
#define IGNORE_IDX 255

typedef float f32x4 __attribute__((ext_vector_type(4)));
typedef int   i32x4 __attribute__((ext_vector_type(4)));

// issue one channel load (nt kept from R7: harmless, avoids L1/L2 pollution)
#define ISSUE(c) x[c] = __builtin_nontemporal_load(base + (size_t)(c) * QPP)
// consume one channel: exp in place + denominator partial sums (order-preserving)
#define PROC(c) do {                                   \
    x[c].x = __expf(x[c].x); s0 += x[c].x;             \
    x[c].y = __expf(x[c].y); s1 += x[c].y;             \
    x[c].z = __expf(x[c].z); s2 += x[c].z;             \
    x[c].w = __expf(x[c].w); s3 += x[c].w; } while (0)
#define SB() __builtin_amdgcn_sched_barrier(0)

__global__ __launch_bounds__(NTHR, 2) void dice_accum(
    const float* __restrict__ logits,
    const int* __restrict__ targets,
    float* __restrict__ part)         // part[NBLK][64]: 0-18 S, 19-37 I, 38-56 cnt
{
    const int tid = blockIdx.x * NTHR + threadIdx.x;

    float accS[CC], accI[CC], accC[CC];
#pragma unroll
    for (int c = 0; c < CC; ++c) { accS[c] = 0.f; accI[c] = 0.f; accC[c] = 0.f; }

#pragma unroll 1                      // keep x[] live set to one iteration
    for (int it = 0; it < NITER; ++it) {
        const int q = tid + it * NTH_TOT;         // quad index
        const int b = q >> 16;                    // q / QPP
        const int hw4 = q & (QPP - 1);
        const f32x4* base = (const f32x4*)logits + (size_t)(b * CC) * QPP + hw4;

        const i32x4 tt = __builtin_nontemporal_load(
            (const i32x4*)(targets + 4 * (size_t)q));

        // ---- Phase A/B fused: pipelined channel loads, groups of 3,
        //      2 groups in flight, consume-on-arrival ----
        f32x4 x[CC];
        float s0 = 0.f, s1 = 0.f, s2 = 0.f, s3 = 0.f;

        ISSUE(0);  ISSUE(1);  ISSUE(2);               // G0
        SB();
        ISSUE(3);  ISSUE(4);  ISSUE(5);               // G1
        SB();
        PROC(0);  PROC(1);  PROC(2);                  // wait G0 (G1 in flight)
        SB();
        ISSUE(6);  ISSUE(7);  ISSUE(8);               // G2
        SB();
        PROC(3);  PROC(4);  PROC(5);
        SB();
        ISSUE(9);  ISSUE(10); ISSUE(11);              // G3
        SB();
        PROC(6);  PROC(7);  PROC(8);
        SB();
        ISSUE(12); ISSUE(13); ISSUE(14);              // G4
        SB();
        PROC(9);  PROC(10); PROC(11);
        SB();
        ISSUE(15); ISSUE(16); ISSUE(17);              // G5
        SB();
        PROC(12); PROC(13); PROC(14);
        SB();
        ISSUE(18);                                    // G6
        SB();
        PROC(15); PROC(16); PROC(17);
        SB();
        PROC(18);

        const float i0 = (tt.x != IGNORE_IDX) ? __builtin_amdgcn_rcpf(s0) : 0.f;
        const float i1 = (tt.y != IGNORE_IDX) ? __builtin_amdgcn_rcpf(s1) : 0.f;
        const float i2 = (tt.z != IGNORE_IDX) ? __builtin_amdgcn_rcpf(s2) : 0.f;
        const float i3 = (tt.w != IGNORE_IDX) ? __builtin_amdgcn_rcpf(s3) : 0.f;

        // ---- Phase C: accumulate (pure VALU) ----
#pragma unroll
        for (int c = 0; c < CC; ++c) {
            accS[c] = fmaf(x[c].x, i0,
                      fmaf(x[c].y, i1,
                      fmaf(x[c].z, i2,
                      fmaf(x[c].w, i3, accS[c]))));
            const bool h0 = (tt.x == c), h1 = (tt.y == c);
            const bool h2 = (tt.z == c), h3 = (tt.w == c);
            accI[c] = fmaf(h0 ? x[c].x : 0.f, i0,
                      fmaf(h1 ? x[c].y : 0.f, i1,
                      fmaf(h2 ? x[c].z : 0.f, i2,
                      fmaf(h3 ? x[c].w : 0.f, i3, accI[c]))));
            accC[c] += (h0 ? 1.f : 0.f) + (h1 ? 1.f : 0.f)
                     + (h2 ? 1.f : 0.f) + (h3 ? 1.f : 0.f);
        }
    }

    // ---- wave-level reduce of the 57 accumulators ----
#pragma unroll
    for (int c = 0; c < CC; ++c) {
        for (int off = 32; off; off >>= 1) {
            accS[c] += __shfl_down(accS[c], off);
            accI[c] += __shfl_down(accI[c], off);
            accC[c] += __shfl_down(accC[c], off);
        }
    }

    __shared__ float s_part[4][64];
    const int wave = threadIdx.x >> 6;
    const int lane = threadIdx.x & 63;
    if (lane == 0) {
#pragma unroll
        for (int c = 0; c < CC; ++c) {
            s_part[wave][c]          = accS[c];
            s_part[wave][CC + c]     = accI[c];
            s_part[wave][2 * CC + c] = accC[c];
        }
#pragma unroll
        for (int c = 3 * CC; c < 64; ++c) s_part[wave][c] = 0.f;  // ws is poisoned
    }
    __syncthreads();
    if (threadIdx.x < 64) {
        float v = s_part[0][threadIdx.x] + s_part[1][threadIdx.x]
                + s_part[2][threadIdx.x] + s_part[3][threadIdx.x];
        part[blockIdx.x * 64 + threadIdx.x] = v;
    }
}

__global__ __launch_bounds__(1024) void dice_final(
    const float* __restrict__ part, float* __restrict__ out)
{
    const int wave = threadIdx.x >> 6;   // 0..15
    const int lane = threadIdx.x & 63;
    float v = 0.f;
    for (int r = wave; r < NBLK; r += 16)
        v += part[r * 64 + lane];        // coalesced 256B rows

    __shared__ float s_red[16][64];
    s_red[wave][lane] = v;
    __syncthreads();

    __shared__ float s_tot[64];
    if (threadIdx.x < 64) {
        float tot = 0.f;
#pragma unroll
        for (int w = 0; w < 16; ++w) tot += s_red[w][threadIdx.x];
        s_tot[threadIdx.x] = tot;
    }
    __syncthreads();

    if (threadIdx.x == 0) {
        float loss = 0.f, totv = 0.f;
#pragma unroll
        for (int c = 0; c < CC; ++c) {
            const float S = s_tot[c];
            const float I = s_tot[CC + c];
            const float N = s_tot[2 * CC + c];
            totv += N;
            loss += 1.f - (2.f * I + 1.f) / (S + N + 1.f);
        }
        out[0] = (totv > 0.f) ? loss * (1.f / (float)CC) : 0.f;
    }
}

extern "C" void kernel_launch(void* const* d_in, const int* in_sizes, int n_in,
                              void* d_out, int out_size, void* d_ws, size_t ws_size,
                              hipStream_t stream) {
    const float* logits = (const float*)d_in[0];
    const int* targets = (const int*)d_in[1];
    float* part = (float*)d_ws;          // 1024*64*4 = 256 KB
    float* out = (float*)d_out;

    dice_accum<<<NBLK, NTHR, 0, stream>>>(logits, targets, part);
    dice_final<<<1, 1024, 0, stream>>>(part, out);
}